// Round 7
// baseline (358.027 us; speedup 1.0000x reference)
//
#include <hip/hip_runtime.h>
#include <stdint.h>

#define BN 8
#define TN 4096
#define CN 512
#define TA 2048
#define RR 1024
#define BASEB 1024
#define MROWS 3072
#define KC 32

typedef _Float16 f16x8 __attribute__((ext_vector_type(8)));
typedef float f32x4 __attribute__((ext_vector_type(4)));
typedef __attribute__((address_space(3))) uint32_t lds_u32_t;
typedef __attribute__((address_space(1))) const uint32_t g_u32_t;

__device__ __forceinline__ unsigned ofloat(float f) {
    unsigned u = __float_as_uint(f);
    return (u & 0x80000000u) ? ~u : (u | 0x80000000u);
}

// ---------- kernel 1: normalize rows of k, split into H(x2^10)/L fp16 planes,
// ---------- deinterleave even rows -> A planes, odd rows -> B planes
__global__ __launch_bounds__(256) void split_kernel(const float* __restrict__ k,
        _Float16* __restrict__ Ahi, _Float16* __restrict__ Alo,
        _Float16* __restrict__ Bhi, _Float16* __restrict__ Blo) {
    int row = blockIdx.x * 4 + (threadIdx.x >> 6);
    int lane = threadIdx.x & 63;
    const float* p = k + (size_t)row * CN;
    float4 v1 = *(const float4*)(p + lane * 8);
    float4 v2 = *(const float4*)(p + lane * 8 + 4);
    float s = v1.x*v1.x + v1.y*v1.y + v1.z*v1.z + v1.w*v1.w
            + v2.x*v2.x + v2.y*v2.y + v2.z*v2.z + v2.w*v2.w;
    #pragma unroll
    for (int off = 32; off > 0; off >>= 1) s += __shfl_xor(s, off);
    float sc = 1024.0f / (sqrtf(s) + 1e-12f);
    float m[8] = {v1.x*sc, v1.y*sc, v1.z*sc, v1.w*sc,
                  v2.x*sc, v2.y*sc, v2.z*sc, v2.w*sc};
    f16x8 H, L;
    #pragma unroll
    for (int jj = 0; jj < 8; ++jj) {
        _Float16 h = (_Float16)m[jj];
        H[jj] = h;
        L[jj] = (_Float16)(m[jj] - (float)h);
    }
    int b = row >> 12;         // row / 4096
    int tt = row & 4095;
    size_t dst = ((size_t)(b * TA + (tt >> 1))) * CN + lane * 8;
    if (tt & 1) { *(f16x8*)(Bhi + dst) = H; *(f16x8*)(Blo + dst) = L; }
    else        { *(f16x8*)(Ahi + dst) = H; *(f16x8*)(Alo + dst) = L; }
}

// ---------- kernel 2: init node keys (hi = ofloat(-inf), lo decodes to j=0)
__global__ void init_kernel(unsigned long long* __restrict__ nodekey) {
    int idx = blockIdx.x * 256 + threadIdx.x;
    if (idx < BN * TA)
        nodekey[idx] = (((unsigned long long)0x007FFFFFu) << 32) | 0xFFFFFFFFull;
}

// ---------- kernel 3: fp16-split MFMA score GEMM + fused row max/argmax ----
// grid (16 i-tiles, 16 j-tiles, 8 batches), 256 thr = 4 waves, 128x128 tile.
// 16x16x32 MFMA (proven: 0 bank conflicts, 39% MfmaUtil at 3 blk/CU).
// Occupancy raised to 5 blocks/CU (64 VGPR, 32KB LDS -> LDS-capped at 5).
__global__ __launch_bounds__(256, 5) void score_mfma_kernel(
        const _Float16* __restrict__ Ahi, const _Float16* __restrict__ Alo,
        const _Float16* __restrict__ Bhi, const _Float16* __restrict__ Blo,
        unsigned long long* __restrict__ nodekey) {
    __shared__ _Float16 lds[4 * 128 * KC];   // 4 planes x 128 rows x 32 halves = 32 KB
    const int b  = blockIdx.z;
    const int i0 = blockIdx.x * 128;
    const int j0 = blockIdx.y * 128;
    const int tid = threadIdx.x;
    const int lane = tid & 63;
    const int w = tid >> 6;
    const int wr = (w >> 1) * 64;
    const int wc = (w & 1) * 64;
    const size_t boff = (size_t)b * TA * CN;

    const _Float16* gbase[4] = {
        Ahi + boff + (size_t)i0 * CN,
        Alo + boff + (size_t)i0 * CN,
        Bhi + boff + (size_t)j0 * CN,
        Blo + boff + (size_t)j0 * CN };

    // staging source geometry (slot s = i*256 + tid; plane = i>>1)
    const int srow = tid >> 2;                       // 0..63 (plus 64 for odd i)
    const int segD = (tid & 3) ^ ((tid >> 3) & 3);   // data seg for swizzled slot

    f32x4 acc[4][4];
    #pragma unroll
    for (int m = 0; m < 4; ++m)
        #pragma unroll
        for (int n = 0; n < 4; ++n) acc[m][n] = (f32x4){0.f, 0.f, 0.f, 0.f};

    const int fr = lane & 15, ks = lane >> 4;
    // per-lane swizzled read offsets (k-invariant, hoisted)
    int aoff[4], boff2[4];
    #pragma unroll
    for (int m = 0; m < 4; ++m) {
        int r = wr + m * 16 + fr;
        aoff[m] = r * KC + (ks ^ ((r >> 1) & 3)) * 8;
    }
    #pragma unroll
    for (int n = 0; n < 4; ++n) {
        int r = wc + n * 16 + fr;
        boff2[n] = r * KC + (ks ^ ((r >> 1) & 3)) * 8;
    }

    for (int kt = 0; kt < CN; kt += KC) {
        // ---- stage 32 KB via 8 global_load_lds (16B/lane, linear LDS dest) ----
        #pragma unroll
        for (int i = 0; i < 8; ++i) {
            const _Float16* gp = gbase[i >> 1]
                + (size_t)((i & 1) * 64 + srow) * CN + kt + segD * 8;
            _Float16* lp = lds + i * 2048 + w * 512;
            __builtin_amdgcn_global_load_lds((g_u32_t*)gp, (lds_u32_t*)lp, 16, 0, 0);
        }
        __syncthreads();   // drains vmcnt -> staged data visible
        // ---- fragments + 48 MFMA ----
        f16x8 bh[4], bl[4];
        #pragma unroll
        for (int n = 0; n < 4; ++n) {
            bh[n] = *(const f16x8*)(&lds[2 * 4096 + boff2[n]]);
            bl[n] = *(const f16x8*)(&lds[3 * 4096 + boff2[n]]);
        }
        #pragma unroll
        for (int m = 0; m < 4; ++m) {
            f16x8 ah = *(const f16x8*)(&lds[0 * 4096 + aoff[m]]);
            f16x8 al = *(const f16x8*)(&lds[1 * 4096 + aoff[m]]);
            #pragma unroll
            for (int n = 0; n < 4; ++n) {
                acc[m][n] = __builtin_amdgcn_mfma_f32_16x16x32_f16(ah, bh[n], acc[m][n], 0, 0, 0);
                acc[m][n] = __builtin_amdgcn_mfma_f32_16x16x32_f16(ah, bl[n], acc[m][n], 0, 0, 0);
                acc[m][n] = __builtin_amdgcn_mfma_f32_16x16x32_f16(al, bh[n], acc[m][n], 0, 0, 0);
            }
        }
        __syncthreads();   // all waves done reading before next stage overwrites
    }

    // ---- epilogue: per-row max/argmax, C/D layout col=lane&15, row=(lane>>4)*4+reg
    const float SC = 1.0f / 1048576.0f;   // 2^-20
    #pragma unroll
    for (int m = 0; m < 4; ++m) {
        #pragma unroll
        for (int reg = 0; reg < 4; ++reg) {
            unsigned bhi = 0u, blo2 = 0u;
            #pragma unroll
            for (int n = 0; n < 4; ++n) {
                float sc = acc[m][n][reg] * SC;
                unsigned j = (unsigned)(j0 + wc + n * 16 + fr);
                unsigned khi = ofloat(sc), klo = 0xFFFFFFFFu - j;
                if (khi > bhi || (khi == bhi && klo > blo2)) { bhi = khi; blo2 = klo; }
            }
            #pragma unroll
            for (int mm2 = 8; mm2 > 0; mm2 >>= 1) {
                unsigned ohi = (unsigned)__shfl_xor((int)bhi, mm2, 16);
                unsigned olo = (unsigned)__shfl_xor((int)blo2, mm2, 16);
                if (ohi > bhi || (ohi == bhi && olo > blo2)) { bhi = ohi; blo2 = olo; }
            }
            if (fr == 0) {
                int i = i0 + wr + m * 16 + ks * 4 + reg;
                if (i != 0) {   // PROTECT_CLS: i==0 stays -inf
                    unsigned long long key = (((unsigned long long)bhi) << 32) | blo2;
                    atomicMax(&nodekey[b * TA + i], key);
                }
            }
        }
    }
}

// ---------- kernel 4a: parallel counting rank -> membership flag -----------
__global__ __launch_bounds__(256) void rank_flag_kernel(
        const unsigned long long* __restrict__ nodekey,
        int* __restrict__ is_src) {
    __shared__ unsigned long long K[2048];
    const int b = blockIdx.y;
    const int t = threadIdx.x;
    for (int i = t; i < 2048; i += 256) {
        unsigned hi = (unsigned)(nodekey[b * TA + i] >> 32);
        K[i] = (((unsigned long long)hi) << 32) | (unsigned)(2047 - i);
    }
    __syncthreads();
    const int i = blockIdx.x * 256 + t;
    const unsigned long long ki = K[i];
    int rank = 0;
    #pragma unroll 8
    for (int j = 0; j < 2048; ++j) rank += (K[j] > ki) ? 1 : 0;
    is_src[b * TA + i] = (rank < RR) ? 1 : 0;   // top-RR node_max are merged
}

// ---------- kernel 4b: per-batch scan (unmerged ranks) + fused source_index
__global__ __launch_bounds__(1024) void scan_si_kernel(const int* __restrict__ is_src,
        const unsigned long long* __restrict__ nodekey,
        int* __restrict__ unm_rank, float* __restrict__ out_si) {
    __shared__ int ps[2048];
    __shared__ unsigned char fl[2048];
    const int b = blockIdx.x;
    const int t = threadIdx.x;
    int s0 = is_src[b * TA + t];
    int s1 = is_src[b * TA + 1024 + t];
    int f0 = 1 - s0, f1 = 1 - s1;
    fl[t] = (unsigned char)s0;
    fl[t + 1024] = (unsigned char)s1;
    ps[t] = f0;
    ps[t + 1024] = f1;
    __syncthreads();
    for (int off = 1; off < 2048; off <<= 1) {
        int v0 = (t >= off) ? ps[t - off] : 0;
        int v1 = ((t + 1024) >= off) ? ps[t + 1024 - off] : 0;
        __syncthreads();
        ps[t] += v0;
        ps[t + 1024] += v1;
        __syncthreads();
    }
    int u0 = ps[t] - f0, u1 = ps[t + 1024] - f1;
    unm_rank[b * TA + t] = u0;
    unm_rank[b * TA + 1024 + t] = u1;
    // fused source_index: even token 2i from node i, odd token 2i+1 = BASEB+i
    #pragma unroll
    for (int h = 0; h < 2; ++h) {
        int i = t + h * 1024;
        int u = h ? u1 : u0;
        int val;
        if (fl[i]) {
            unsigned j = 0xFFFFFFFFu - (unsigned)(nodekey[b * TA + i] & 0xFFFFFFFFull);
            val = BASEB + (int)j;
        } else {
            val = u;
        }
        out_si[(size_t)b * TN + 2 * i]     = (float)val;
        out_si[(size_t)b * TN + 2 * i + 1] = (float)(BASEB + i);
    }
}

// ---------- kernel 5: copy unmerged + dst base rows (proven) ---------------
__global__ __launch_bounds__(128) void copy_kernel(const float* __restrict__ x,
                                                   const int* __restrict__ is_src,
                                                   const int* __restrict__ unm_rank,
                                                   float* __restrict__ out) {
    const int b = blockIdx.y;
    const int tt = blockIdx.x;
    const float* src;
    float* dst;
    if (tt < 2048) {
        int i = tt;
        if (is_src[b * TA + i]) return;
        src = x + ((size_t)b * TN + 2 * i) * CN;
        dst = out + ((size_t)b * MROWS + unm_rank[b * TA + i]) * CN;
    } else {
        int j = tt - 2048;
        src = x + ((size_t)b * TN + 2 * j + 1) * CN;
        dst = out + ((size_t)b * MROWS + BASEB + j) * CN;
    }
    ((float4*)dst)[threadIdx.x] = ((const float4*)src)[threadIdx.x];
}

// ---------- kernel 6: scatter-add merged sources (proven) ------------------
__global__ __launch_bounds__(256) void scatter_kernel(const float* __restrict__ x,
                                                      const int* __restrict__ is_src,
                                                      const unsigned long long* __restrict__ nodekey,
                                                      float* __restrict__ out) {
    const int b = blockIdx.y;
    const int i = blockIdx.x;
    if (!is_src[b * TA + i]) return;
    unsigned j = 0xFFFFFFFFu - (unsigned)(nodekey[b * TA + i] & 0xFFFFFFFFull);
    const float* src = x + ((size_t)b * TN + 2 * i) * CN;
    float* dst = out + ((size_t)b * MROWS + BASEB + j) * CN;
    for (int c = threadIdx.x; c < CN; c += 256) atomicAdd(&dst[c], src[c]);
}

extern "C" void kernel_launch(void* const* d_in, const int* in_sizes, int n_in,
                              void* d_out, int out_size, void* d_ws, size_t ws_size,
                              hipStream_t stream) {
    const float* x = (const float*)d_in[0];
    const float* k = (const float*)d_in[1];
    float* out = (float*)d_out;
    float* out_si = out + (size_t)BN * MROWS * CN;

    char* ws = (char*)d_ws;
    const size_t PLANE = (size_t)BN * TA * CN;          // 8,388,608 elements
    _Float16* Ahi = (_Float16*)ws;
    _Float16* Alo = Ahi + PLANE;
    _Float16* Bhi = Alo + PLANE;
    _Float16* Blo = Bhi + PLANE;
    char* tail = ws + 4 * PLANE * sizeof(_Float16);     // 64 MB
    unsigned long long* nodekey = (unsigned long long*)(tail);
    int* is_src   = (int*)(tail + 128 * 1024);
    int* unm_rank = (int*)(tail + 192 * 1024);

    split_kernel<<<dim3(BN * TN / 4), dim3(256), 0, stream>>>(k, Ahi, Alo, Bhi, Blo);
    init_kernel<<<dim3((BN * TA + 255) / 256), dim3(256), 0, stream>>>(nodekey);
    score_mfma_kernel<<<dim3(16, 16, BN), dim3(256), 0, stream>>>(Ahi, Alo, Bhi, Blo, nodekey);
    rank_flag_kernel<<<dim3(8, BN), dim3(256), 0, stream>>>(nodekey, is_src);
    scan_si_kernel<<<dim3(BN), dim3(1024), 0, stream>>>(is_src, nodekey, unm_rank, out_si);
    copy_kernel<<<dim3(4096, BN), dim3(128), 0, stream>>>(x, is_src, unm_rank, out);
    scatter_kernel<<<dim3(2048, BN), dim3(256), 0, stream>>>(x, is_src, nodekey, out);
}

// Round 8
// 204.757 us; speedup vs baseline: 1.7485x; 1.7485x over previous
//
#include <hip/hip_runtime.h>
#include <stdint.h>

#define BN 8
#define TN 4096
#define CN 512
#define TA 2048
#define RR 1024
#define BASEB 1024
#define MROWS 3072
#define KC 32

typedef _Float16 f16x8 __attribute__((ext_vector_type(8)));
typedef float f32x4 __attribute__((ext_vector_type(4)));
typedef __attribute__((address_space(3))) uint32_t lds_u32_t;
typedef __attribute__((address_space(1))) const uint32_t g_u32_t;

__device__ __forceinline__ unsigned ofloat(float f) {
    unsigned u = __float_as_uint(f);
    return (u & 0x80000000u) ? ~u : (u | 0x80000000u);
}

// ---------- kernel 1: normalize rows of k, split into H(x2^10)/L fp16 planes,
// ---------- deinterleave even rows -> A planes, odd rows -> B planes
__global__ __launch_bounds__(256) void split_kernel(const float* __restrict__ k,
        _Float16* __restrict__ Ahi, _Float16* __restrict__ Alo,
        _Float16* __restrict__ Bhi, _Float16* __restrict__ Blo) {
    int row = blockIdx.x * 4 + (threadIdx.x >> 6);
    int lane = threadIdx.x & 63;
    const float* p = k + (size_t)row * CN;
    float4 v1 = *(const float4*)(p + lane * 8);
    float4 v2 = *(const float4*)(p + lane * 8 + 4);
    float s = v1.x*v1.x + v1.y*v1.y + v1.z*v1.z + v1.w*v1.w
            + v2.x*v2.x + v2.y*v2.y + v2.z*v2.z + v2.w*v2.w;
    #pragma unroll
    for (int off = 32; off > 0; off >>= 1) s += __shfl_xor(s, off);
    float sc = 1024.0f / (sqrtf(s) + 1e-12f);
    float m[8] = {v1.x*sc, v1.y*sc, v1.z*sc, v1.w*sc,
                  v2.x*sc, v2.y*sc, v2.z*sc, v2.w*sc};
    f16x8 H, L;
    #pragma unroll
    for (int jj = 0; jj < 8; ++jj) {
        _Float16 h = (_Float16)m[jj];
        H[jj] = h;
        L[jj] = (_Float16)(m[jj] - (float)h);
    }
    int b = row >> 12;         // row / 4096
    int tt = row & 4095;
    size_t dst = ((size_t)(b * TA + (tt >> 1))) * CN + lane * 8;
    if (tt & 1) { *(f16x8*)(Bhi + dst) = H; *(f16x8*)(Blo + dst) = L; }
    else        { *(f16x8*)(Ahi + dst) = H; *(f16x8*)(Alo + dst) = L; }
}

// ---------- kernel 2: init node keys (hi = ofloat(-inf), lo decodes to j=0)
__global__ void init_kernel(unsigned long long* __restrict__ nodekey) {
    int idx = blockIdx.x * 256 + threadIdx.x;
    if (idx < BN * TA)
        nodekey[idx] = (((unsigned long long)0x007FFFFFu) << 32) | 0xFFFFFFFFull;
}

// ---------- kernel 3: fp16-split MFMA score GEMM + fused row max/argmax ----
// grid (16 i-tiles, 16 j-tiles, 8 batches), 256 thr = 4 waves, 128x128 tile.
// 16x16x32 MFMA (proven: 0 bank conflicts, 119us at bound 3).
// True footprint = 64 arch VGPR + 64 acc = 128 regs -> exactly 4 waves/SIMD.
// bound 5 (budget 96 < 128) spilled: WRITE_SIZE 666MB. bound 4 is the max
// spill-free occupancy.
__global__ __launch_bounds__(256, 4) void score_mfma_kernel(
        const _Float16* __restrict__ Ahi, const _Float16* __restrict__ Alo,
        const _Float16* __restrict__ Bhi, const _Float16* __restrict__ Blo,
        unsigned long long* __restrict__ nodekey) {
    __shared__ _Float16 lds[4 * 128 * KC];   // 4 planes x 128 rows x 32 halves = 32 KB
    const int b  = blockIdx.z;
    const int i0 = blockIdx.x * 128;
    const int j0 = blockIdx.y * 128;
    const int tid = threadIdx.x;
    const int lane = tid & 63;
    const int w = tid >> 6;
    const int wr = (w >> 1) * 64;
    const int wc = (w & 1) * 64;
    const size_t boff = (size_t)b * TA * CN;

    const _Float16* gbase[4] = {
        Ahi + boff + (size_t)i0 * CN,
        Alo + boff + (size_t)i0 * CN,
        Bhi + boff + (size_t)j0 * CN,
        Blo + boff + (size_t)j0 * CN };

    // staging source geometry (slot s = i*256 + tid; plane = i>>1)
    const int srow = tid >> 2;                       // 0..63 (plus 64 for odd i)
    const int segD = (tid & 3) ^ ((tid >> 3) & 3);   // data seg for swizzled slot

    f32x4 acc[4][4];
    #pragma unroll
    for (int m = 0; m < 4; ++m)
        #pragma unroll
        for (int n = 0; n < 4; ++n) acc[m][n] = (f32x4){0.f, 0.f, 0.f, 0.f};

    const int fr = lane & 15, ks = lane >> 4;
    // per-lane swizzled read offsets (k-invariant, hoisted)
    int aoff[4], boff2[4];
    #pragma unroll
    for (int m = 0; m < 4; ++m) {
        int r = wr + m * 16 + fr;
        aoff[m] = r * KC + (ks ^ ((r >> 1) & 3)) * 8;
    }
    #pragma unroll
    for (int n = 0; n < 4; ++n) {
        int r = wc + n * 16 + fr;
        boff2[n] = r * KC + (ks ^ ((r >> 1) & 3)) * 8;
    }

    for (int kt = 0; kt < CN; kt += KC) {
        // ---- stage 32 KB via 8 global_load_lds (16B/lane, linear LDS dest) ----
        #pragma unroll
        for (int i = 0; i < 8; ++i) {
            const _Float16* gp = gbase[i >> 1]
                + (size_t)((i & 1) * 64 + srow) * CN + kt + segD * 8;
            _Float16* lp = lds + i * 2048 + w * 512;
            __builtin_amdgcn_global_load_lds((g_u32_t*)gp, (lds_u32_t*)lp, 16, 0, 0);
        }
        __syncthreads();   // drains vmcnt -> staged data visible
        // ---- fragments + 48 MFMA ----
        f16x8 bh[4], bl[4];
        #pragma unroll
        for (int n = 0; n < 4; ++n) {
            bh[n] = *(const f16x8*)(&lds[2 * 4096 + boff2[n]]);
            bl[n] = *(const f16x8*)(&lds[3 * 4096 + boff2[n]]);
        }
        #pragma unroll
        for (int m = 0; m < 4; ++m) {
            f16x8 ah = *(const f16x8*)(&lds[0 * 4096 + aoff[m]]);
            f16x8 al = *(const f16x8*)(&lds[1 * 4096 + aoff[m]]);
            #pragma unroll
            for (int n = 0; n < 4; ++n) {
                acc[m][n] = __builtin_amdgcn_mfma_f32_16x16x32_f16(ah, bh[n], acc[m][n], 0, 0, 0);
                acc[m][n] = __builtin_amdgcn_mfma_f32_16x16x32_f16(ah, bl[n], acc[m][n], 0, 0, 0);
                acc[m][n] = __builtin_amdgcn_mfma_f32_16x16x32_f16(al, bh[n], acc[m][n], 0, 0, 0);
            }
        }
        __syncthreads();   // all waves done reading before next stage overwrites
    }

    // ---- epilogue: per-row max/argmax, C/D layout col=lane&15, row=(lane>>4)*4+reg
    const float SC = 1.0f / 1048576.0f;   // 2^-20
    #pragma unroll
    for (int m = 0; m < 4; ++m) {
        #pragma unroll
        for (int reg = 0; reg < 4; ++reg) {
            unsigned bhi = 0u, blo2 = 0u;
            #pragma unroll
            for (int n = 0; n < 4; ++n) {
                float sc = acc[m][n][reg] * SC;
                unsigned j = (unsigned)(j0 + wc + n * 16 + fr);
                unsigned khi = ofloat(sc), klo = 0xFFFFFFFFu - j;
                if (khi > bhi || (khi == bhi && klo > blo2)) { bhi = khi; blo2 = klo; }
            }
            #pragma unroll
            for (int mm2 = 8; mm2 > 0; mm2 >>= 1) {
                unsigned ohi = (unsigned)__shfl_xor((int)bhi, mm2, 16);
                unsigned olo = (unsigned)__shfl_xor((int)blo2, mm2, 16);
                if (ohi > bhi || (ohi == bhi && olo > blo2)) { bhi = ohi; blo2 = olo; }
            }
            if (fr == 0) {
                int i = i0 + wr + m * 16 + ks * 4 + reg;
                if (i != 0) {   // PROTECT_CLS: i==0 stays -inf
                    unsigned long long key = (((unsigned long long)bhi) << 32) | blo2;
                    atomicMax(&nodekey[b * TA + i], key);
                }
            }
        }
    }
}

// ---------- kernel 4a: parallel counting rank -> membership flag -----------
__global__ __launch_bounds__(256) void rank_flag_kernel(
        const unsigned long long* __restrict__ nodekey,
        int* __restrict__ is_src) {
    __shared__ unsigned long long K[2048];
    const int b = blockIdx.y;
    const int t = threadIdx.x;
    for (int i = t; i < 2048; i += 256) {
        unsigned hi = (unsigned)(nodekey[b * TA + i] >> 32);
        K[i] = (((unsigned long long)hi) << 32) | (unsigned)(2047 - i);
    }
    __syncthreads();
    const int i = blockIdx.x * 256 + t;
    const unsigned long long ki = K[i];
    int rank = 0;
    #pragma unroll 8
    for (int j = 0; j < 2048; ++j) rank += (K[j] > ki) ? 1 : 0;
    is_src[b * TA + i] = (rank < RR) ? 1 : 0;   // top-RR node_max are merged
}

// ---------- kernel 4b: per-batch scan (unmerged ranks) + fused source_index
__global__ __launch_bounds__(1024) void scan_si_kernel(const int* __restrict__ is_src,
        const unsigned long long* __restrict__ nodekey,
        int* __restrict__ unm_rank, float* __restrict__ out_si) {
    __shared__ int ps[2048];
    __shared__ unsigned char fl[2048];
    const int b = blockIdx.x;
    const int t = threadIdx.x;
    int s0 = is_src[b * TA + t];
    int s1 = is_src[b * TA + 1024 + t];
    int f0 = 1 - s0, f1 = 1 - s1;
    fl[t] = (unsigned char)s0;
    fl[t + 1024] = (unsigned char)s1;
    ps[t] = f0;
    ps[t + 1024] = f1;
    __syncthreads();
    for (int off = 1; off < 2048; off <<= 1) {
        int v0 = (t >= off) ? ps[t - off] : 0;
        int v1 = ((t + 1024) >= off) ? ps[t + 1024 - off] : 0;
        __syncthreads();
        ps[t] += v0;
        ps[t + 1024] += v1;
        __syncthreads();
    }
    int u0 = ps[t] - f0, u1 = ps[t + 1024] - f1;
    unm_rank[b * TA + t] = u0;
    unm_rank[b * TA + 1024 + t] = u1;
    // fused source_index: even token 2i from node i, odd token 2i+1 = BASEB+i
    #pragma unroll
    for (int h = 0; h < 2; ++h) {
        int i = t + h * 1024;
        int u = h ? u1 : u0;
        int val;
        if (fl[i]) {
            unsigned j = 0xFFFFFFFFu - (unsigned)(nodekey[b * TA + i] & 0xFFFFFFFFull);
            val = BASEB + (int)j;
        } else {
            val = u;
        }
        out_si[(size_t)b * TN + 2 * i]     = (float)val;
        out_si[(size_t)b * TN + 2 * i + 1] = (float)(BASEB + i);
    }
}

// ---------- kernel 5: copy unmerged + dst base rows (proven) ---------------
__global__ __launch_bounds__(128) void copy_kernel(const float* __restrict__ x,
                                                   const int* __restrict__ is_src,
                                                   const int* __restrict__ unm_rank,
                                                   float* __restrict__ out) {
    const int b = blockIdx.y;
    const int tt = blockIdx.x;
    const float* src;
    float* dst;
    if (tt < 2048) {
        int i = tt;
        if (is_src[b * TA + i]) return;
        src = x + ((size_t)b * TN + 2 * i) * CN;
        dst = out + ((size_t)b * MROWS + unm_rank[b * TA + i]) * CN;
    } else {
        int j = tt - 2048;
        src = x + ((size_t)b * TN + 2 * j + 1) * CN;
        dst = out + ((size_t)b * MROWS + BASEB + j) * CN;
    }
    ((float4*)dst)[threadIdx.x] = ((const float4*)src)[threadIdx.x];
}

// ---------- kernel 6: scatter-add merged sources (proven) ------------------
__global__ __launch_bounds__(256) void scatter_kernel(const float* __restrict__ x,
                                                      const int* __restrict__ is_src,
                                                      const unsigned long long* __restrict__ nodekey,
                                                      float* __restrict__ out) {
    const int b = blockIdx.y;
    const int i = blockIdx.x;
    if (!is_src[b * TA + i]) return;
    unsigned j = 0xFFFFFFFFu - (unsigned)(nodekey[b * TA + i] & 0xFFFFFFFFull);
    const float* src = x + ((size_t)b * TN + 2 * i) * CN;
    float* dst = out + ((size_t)b * MROWS + BASEB + j) * CN;
    for (int c = threadIdx.x; c < CN; c += 256) atomicAdd(&dst[c], src[c]);
}

extern "C" void kernel_launch(void* const* d_in, const int* in_sizes, int n_in,
                              void* d_out, int out_size, void* d_ws, size_t ws_size,
                              hipStream_t stream) {
    const float* x = (const float*)d_in[0];
    const float* k = (const float*)d_in[1];
    float* out = (float*)d_out;
    float* out_si = out + (size_t)BN * MROWS * CN;

    char* ws = (char*)d_ws;
    const size_t PLANE = (size_t)BN * TA * CN;          // 8,388,608 elements
    _Float16* Ahi = (_Float16*)ws;
    _Float16* Alo = Ahi + PLANE;
    _Float16* Bhi = Alo + PLANE;
    _Float16* Blo = Bhi + PLANE;
    char* tail = ws + 4 * PLANE * sizeof(_Float16);     // 64 MB
    unsigned long long* nodekey = (unsigned long long*)(tail);
    int* is_src   = (int*)(tail + 128 * 1024);
    int* unm_rank = (int*)(tail + 192 * 1024);

    split_kernel<<<dim3(BN * TN / 4), dim3(256), 0, stream>>>(k, Ahi, Alo, Bhi, Blo);
    init_kernel<<<dim3((BN * TA + 255) / 256), dim3(256), 0, stream>>>(nodekey);
    score_mfma_kernel<<<dim3(16, 16, BN), dim3(256), 0, stream>>>(Ahi, Alo, Bhi, Blo, nodekey);
    rank_flag_kernel<<<dim3(8, BN), dim3(256), 0, stream>>>(nodekey, is_src);
    scan_si_kernel<<<dim3(BN), dim3(1024), 0, stream>>>(is_src, nodekey, unm_rank, out_si);
    copy_kernel<<<dim3(4096, BN), dim3(128), 0, stream>>>(x, is_src, unm_rank, out);
    scatter_kernel<<<dim3(2048, BN), dim3(256), 0, stream>>>(x, is_src, nodekey, out);
}